// Round 10
// baseline (550.347 us; speedup 1.0000x reference)
//
#include <hip/hip_runtime.h>
#include <cstdint>
#include <cstddef>

typedef unsigned short u16;
using half4 = __attribute__((ext_vector_type(4))) _Float16;
using half8 = __attribute__((ext_vector_type(8))) _Float16;
using f32x4 = __attribute__((ext_vector_type(4))) float;
using f4    = __attribute__((ext_vector_type(4))) float;

#define B_    16
#define C_    256
#define H_    128
#define W_    128
#define C4_   64
#define COUT_ 256
#define HW_   (H_ * W_)

#define T_S       72    // kernel1 T [pixel][c-quarter]: 64 + 8 pad (octet-swizzled)
#define QK_S      72    // kernel2 Q/K [h][d]: 64 + 8 pad
#define P_S       136   // kernel2 P   [h][g]: 128 + 8 pad
#define XP_S      140   // kernel2 epilogue transpose tile [c][h]
#define O_S       72    // kernel1 out tile [pixel][d]: 64 + 8 pad

#define Q_ELEMS   ((size_t)B_ * W_ * H_ * C4_)      // 16,777,216
#define V_ELEMS   ((size_t)B_ * W_ * H_ * COUT_)    // 67,108,864
#define W16_ELEMS ((size_t)(C4_ * C_ + C4_ * C_ + COUT_ * C_))  // 98,304
#define WS_NEED   ((2 * Q_ELEMS + 2 * V_ELEMS + W16_ELEMS) * 2)

__device__ __forceinline__ u16 f16_rn(float f) {
  _Float16 h = (_Float16)f;   // RN
  return __builtin_bit_cast(u16, h);
}

__device__ __forceinline__ void gload16(const void* g, void* l) {
  __builtin_amdgcn_global_load_lds(
      (const __attribute__((address_space(1))) void*)g,
      (__attribute__((address_space(3))) void*)l, 16, 0, 0);
}

// ---------------------------------------------------------------------------
// Kernel 0: one-time fp32 -> fp16 weight conversion into ws.
// ---------------------------------------------------------------------------
__global__ void __launch_bounds__(256) wconv_kernel(
    const float* __restrict__ Wk, const float* __restrict__ Wq,
    const float* __restrict__ Wv, u16* __restrict__ W16) {
  const int bid = blockIdx.x;
  const int t   = threadIdx.x;
  const float* src;
  u16* dst;
  int idx;
  if (bid < 16)      { src = Wk; dst = W16;                 idx = bid * 1024 + t * 4; }
  else if (bid < 32) { src = Wq; dst = W16 + C4_ * C_;      idx = (bid - 16) * 1024 + t * 4; }
  else               { src = Wv; dst = W16 + 2 * C4_ * C_;  idx = (bid - 32) * 1024 + t * 4; }
  f4 v = *reinterpret_cast<const f4*>(src + idx);
  half4 h;
#pragma unroll
  for (int i = 0; i < 4; ++i) h[i] = (_Float16)v[i];
  *reinterpret_cast<half4*>(dst + idx) = h;
}

// ---------------------------------------------------------------------------
// Kernel 1: Q/K/V projections — PIXEL-OCTET tiles (8 w x 8 h), p = w*8 + hl.
// R6/R8/R9 all hit ~272 us with three different staging schemes -> staging
// was never the limiter; the common element was the V epilogue's 64 scattered
// 2-B stores/thread (~17M partial-line L2 write txns). With h-minor pixel
// tiles each block owns all 8 h of every 16-B V unit:
//   V store = half4/lane, lanes tile 256-B contiguous segments (dense),
//   16 store instrs/wave (was 64 scatter instrs).
// Vws fragment layout [b][w][g>>3][c][g&7] is UNCHANGED (attn untouched).
// Input reads: 32-B segments; wt-pair siblings (sharing each 64-B line) are
// same-XCD + adjacent-dispatch (bid = xcd + wtlow*8 + ggg*16), and each XCD
// owns a disjoint w-stripe of both inputs and outputs.
// Pipeline (counted-vmcnt quarters) kept from R9.
// ---------------------------------------------------------------------------
__device__ __forceinline__ const half8* afragq(const u16* __restrict__ T,
                                               int prow, int ksl, int lg) {
  int oct = (ksl * 4 + lg) ^ ((prow >> 2) & 7);
  return reinterpret_cast<const half8*>(&T[prow * T_S + oct * 8]);
}

__device__ __forceinline__ const half8* whfrag(const u16* __restrict__ Wm16,
                                               int row, int ks, int lg) {
  return reinterpret_cast<const half8*>(Wm16 + (size_t)row * C_ + ks * 32 + lg * 8);
}

__global__ void __launch_bounds__(256, 3) qkv_kernel(
    const float* __restrict__ flow, const float* __restrict__ de_out,
    const u16* __restrict__ W16,
    const float* __restrict__ bq, const float* __restrict__ bk,
    const float* __restrict__ bv,
    u16* __restrict__ Qws, u16* __restrict__ Kws, u16* __restrict__ Vws) {
  __shared__ __align__(16) unsigned char ldsraw[2 * 16384 + 64 * T_S * 2];
  float* Fbuf[2] = {reinterpret_cast<float*>(ldsraw),
                    reinterpret_cast<float*>(ldsraw + 16384)};
  u16* T = reinterpret_cast<u16*>(ldsraw + 32768);        // [64 p][72] fp16 quarter
  u16* O = reinterpret_cast<u16*>(ldsraw);                // [64 p][72] out tile

  const int t    = threadIdx.x;
  const int bid  = blockIdx.x;
  // bid = xcd + wtlow*8 + ggg*16 ; wtp == xcd (w-stripe per XCD)
  const int xcd    = bid & 7;
  const int wtlow  = (bid >> 3) & 1;
  const int ggg    = bid >> 4;           // [0,512)
  const int wt     = xcd * 2 + wtlow;    // [0,16) : w in [wt*8, wt*8+8)
  const int h8     = ggg & 15;           // h in [h8*8, h8*8+8)
  const int b      = (ggg >> 4) & 15;
  const int srcsel = ggg >> 8;
  const int lane = t & 63;
  const int wv   = t >> 6;
  const int col  = lane & 15;
  const int lg   = lane >> 4;

  const u16* Wk16 = W16;
  const u16* Wq16 = W16 + C4_ * C_;
  const u16* Wv16 = W16 + 2 * C4_ * C_;

  const float* src = (srcsel ? de_out : flow) +
                     (size_t)b * C_ * HW_ + (size_t)(h8 * 8) * W_ + wt * 8;

  f32x4 zero = {0.f, 0.f, 0.f, 0.f};
  f32x4 acc0[4];                 // K (srcsel=0) or Q (srcsel=1), m-tiles
  f32x4 accV[4][4];              // V [c-tile j][m-tile]
#pragma unroll
  for (int i = 0; i < 4; ++i) acc0[i] = zero;
#pragma unroll
  for (int j = 0; j < 4; ++j)
#pragma unroll
    for (int i = 0; i < 4; ++i) accV[j][i] = zero;

  // stage lane mapping: per instr 4 c-rows; lane l -> c_off=l>>4, hl=(l>>1)&7,
  // w4=(l&1)*4 ; LDS F[c_loc][hl][w8] linear (lane*16 B), global 16-B contiguous.
#define ISSUE_QTR(FDST, CBASE)                                               \
  {                                                                          \
    _Pragma("unroll") for (int i = 0; i < 4; ++i) {                          \
      const int rr0 = wv * 16 + i * 4;                                       \
      gload16(src + (size_t)((CBASE) + rr0 + (lane >> 4)) * HW_ +            \
                  ((lane >> 1) & 7) * W_ + (lane & 1) * 4,                   \
              (FDST) + rr0 * 64);                                            \
    }                                                                        \
  }

  // ---- prologue: issue quarter 0 ----
  ISSUE_QTR(Fbuf[0], 0)

#pragma unroll
  for (int q = 0; q < 4; ++q) {
    float* Fc = Fbuf[q & 1];
    float* Fn = Fbuf[(q + 1) & 1];
    if (q < 3) {
      ISSUE_QTR(Fn, (q + 1) * 64)
      asm volatile("s_waitcnt vmcnt(4) lgkmcnt(0)\ns_barrier" ::: "memory");
    } else {
      asm volatile("s_waitcnt vmcnt(0) lgkmcnt(0)\ns_barrier" ::: "memory");
    }
    __builtin_amdgcn_sched_barrier(0);

    // ---- convert: Fc[c][hl][w8] fp32 -> T[p = w*8+hl][c_loc] fp16 (octet XOR)
#pragma unroll
    for (int i = 0; i < 2; ++i) {
      const int flat = i * 256 + t;            // [0,512)
      const int cp = flat >> 4;                // c-pair [0,32)
      const int hl = (flat >> 1) & 7;
      const int wq = flat & 1;                 // w-quad (0: w 0-3, 1: w 4-7)
      const f4 fa = *reinterpret_cast<const f4*>(&Fc[(2 * cp) * 64 + hl * 8 + wq * 4]);
      const f4 fb = *reinterpret_cast<const f4*>(&Fc[(2 * cp + 1) * 64 + hl * 8 + wq * 4]);
      const int c_loc = 2 * cp;
#pragma unroll
      for (int j = 0; j < 4; ++j) {
        const int w = wq * 4 + j;
        const int p = w * 8 + hl;
        const int oct = (cp >> 2) ^ ((p >> 2) & 7);
        uint32_t pk = (uint32_t)f16_rn(fa[j]) | ((uint32_t)f16_rn(fb[j]) << 16);
        *reinterpret_cast<uint32_t*>(&T[p * T_S + oct * 8 + (c_loc & 7)]) = pk;
      }
    }
    asm volatile("s_waitcnt lgkmcnt(0)\ns_barrier" ::: "memory");
    __builtin_amdgcn_sched_barrier(0);

    // ---- MFMA this quarter's two k-chunks ----
#pragma unroll
    for (int ksl = 0; ksl < 2; ++ksl) {
      const int ks = 2 * q + ksl;
      if (srcsel == 0) {
        const half8 bK = *whfrag(Wk16, wv * 16 + col, ks, lg);
        half8 bV[4];
#pragma unroll
        for (int j = 0; j < 4; ++j)
          bV[j] = *whfrag(Wv16, (wv * 4 + j) * 16 + col, ks, lg);
#pragma unroll
        for (int mt = 0; mt < 4; ++mt) {
          const half8 afr = *afragq(T, mt * 16 + col, ksl, lg);
          acc0[mt] = __builtin_amdgcn_mfma_f32_16x16x32_f16(afr, bK, acc0[mt], 0, 0, 0);
#pragma unroll
          for (int j = 0; j < 4; ++j)
            accV[j][mt] =
                __builtin_amdgcn_mfma_f32_16x16x32_f16(afr, bV[j], accV[j][mt], 0, 0, 0);
        }
      } else {
        const half8 bQ = *whfrag(Wq16, wv * 16 + col, ks, lg);
#pragma unroll
        for (int mt = 0; mt < 4; ++mt) {
          const half8 afr = *afragq(T, mt * 16 + col, ksl, lg);
          acc0[mt] = __builtin_amdgcn_mfma_f32_16x16x32_f16(afr, bQ, acc0[mt], 0, 0, 0);
        }
      }
    }
  }

  // ---- epilogue ----
  // row m = mt*16 + lg*4 + r  ->  pixel p = m : w_loc = p>>3, hl = p&7.
  if (srcsel == 0) {
    {  // K via LDS O-tile [p][d], then per-w 1-KB contiguous runs
      const float bias = bk[wv * 16 + col];
      __syncthreads();
#pragma unroll
      for (int mt = 0; mt < 4; ++mt)
#pragma unroll
        for (int r = 0; r < 4; ++r)
          O[(mt * 16 + lg * 4 + r) * O_S + wv * 16 + col] = f16_rn(acc0[mt][r] + bias);
      __syncthreads();
#pragma unroll
      for (int i = 0; i < 2; ++i) {
        const int item = i * 256 + t;      // [0,512)
        const int p  = item >> 3;          // [0,64)
        const int d0 = (item & 7) * 8;
        *reinterpret_cast<half8*>(
            &Kws[(((size_t)b * W_ + wt * 8 + (p >> 3)) * H_ + h8 * 8 + (p & 7)) * C4_ + d0]) =
            *reinterpret_cast<const half8*>(&O[p * O_S + d0]);
      }
    }
    // V: DENSE stores. lane (lg,col), m-tile mt: w_loc = mt*2+(lg>>1),
    // hl0 = (lg&1)*4; half4 = 4 consecutive hl -> 8 B; 16 cols tile 256 B.
    {
      const size_t colbase = ((size_t)b * W_ + wt * 8) * 32768;
#pragma unroll
      for (int j = 0; j < 4; ++j) {
        const int co = (wv * 4 + j) * 16 + col;
        const float bias = bv[co];
#pragma unroll
        for (int mt = 0; mt < 4; ++mt) {
          const int w_loc = mt * 2 + (lg >> 1);
          const int hl0   = (lg & 1) * 4;
          half4 pk;
#pragma unroll
          for (int r = 0; r < 4; ++r) pk[r] = (_Float16)(accV[j][mt][r] + bias);
          *reinterpret_cast<half4*>(
              Vws + colbase + (size_t)w_loc * 32768 + (size_t)(h8 * COUT_ + co) * 8 + hl0) = pk;
        }
      }
    }
  } else {
    const float bias = bq[wv * 16 + col];
    __syncthreads();
#pragma unroll
    for (int mt = 0; mt < 4; ++mt)
#pragma unroll
      for (int r = 0; r < 4; ++r)
        O[(mt * 16 + lg * 4 + r) * O_S + wv * 16 + col] = f16_rn(acc0[mt][r] + bias);
    __syncthreads();
#pragma unroll
    for (int i = 0; i < 2; ++i) {
      const int item = i * 256 + t;
      const int p  = item >> 3;
      const int d0 = (item & 7) * 8;
      *reinterpret_cast<half8*>(
          &Qws[(((size_t)b * W_ + wt * 8 + (p >> 3)) * H_ + h8 * 8 + (p & 7)) * C4_ + d0]) =
          *reinterpret_cast<const half8*>(&O[p * O_S + d0]);
    }
  }
#undef ISSUE_QTR
}

// ---------------------------------------------------------------------------
// Kernel 2: per-(b,w)-column attention (unchanged).
// ---------------------------------------------------------------------------
template <int EPI>
__global__ void __launch_bounds__(256) attn_kernel(
    const u16* __restrict__ Qws, const u16* __restrict__ Kws,
    const u16* __restrict__ Vws, u16* __restrict__ out_tmp,
    float* __restrict__ out) {
  __shared__ __align__(16) u16 ldsQK[2 * 128 * QK_S];  // P and epi-tile overlay

  const int t   = threadIdx.x;
  const int bid = blockIdx.x;
  const int sw  = (bid & 7) * 256 + (bid >> 3);  // bijective
  const int b   = sw >> 7;
  const int w   = sw & 127;
  const int lane = t & 63;
  const int wv   = t >> 6;
  const int col  = lane & 15;
  const int lg   = lane >> 4;

  const u16* qc    = Qws + ((size_t)b * W_ + w) * H_ * C4_;
  const u16* kc    = Kws + ((size_t)b * W_ + w) * H_ * C4_;
  const u16* vbase = Vws + (size_t)(b * W_ + w) * 32768;

  u16* ldsQ = ldsQK;
  u16* ldsK = ldsQK + 128 * QK_S;

#pragma unroll
  for (int i = 0; i < 4; ++i) {
    int item = i * 256 + t;
    int hh   = item >> 3;
    int d0   = (item & 7) * 8;
    *reinterpret_cast<half8*>(&ldsQ[hh * QK_S + d0]) =
        *reinterpret_cast<const half8*>(qc + item * 8);
    *reinterpret_cast<half8*>(&ldsK[hh * QK_S + d0]) =
        *reinterpret_cast<const half8*>(kc + item * 8);
  }
  __syncthreads();

  f32x4 zero = {0.f, 0.f, 0.f, 0.f};
  f32x4 e[2][8];
#pragma unroll
  for (int ht = 0; ht < 2; ++ht)
#pragma unroll
    for (int gt = 0; gt < 8; ++gt) e[ht][gt] = zero;

#pragma unroll
  for (int ks = 0; ks < 2; ++ks) {
    half8 aq[2];
#pragma unroll
    for (int ht = 0; ht < 2; ++ht)
      aq[ht] = *reinterpret_cast<const half8*>(
          &ldsQ[(wv * 32 + ht * 16 + col) * QK_S + ks * 32 + lg * 8]);
#pragma unroll
    for (int gt = 0; gt < 8; ++gt) {
      const half8 bk_ = *reinterpret_cast<const half8*>(
          &ldsK[(gt * 16 + col) * QK_S + ks * 32 + lg * 8]);
#pragma unroll
      for (int ht = 0; ht < 2; ++ht)
        e[ht][gt] = __builtin_amdgcn_mfma_f32_16x16x32_f16(aq[ht], bk_, e[ht][gt], 0, 0, 0);
    }
  }
  __syncthreads();  // Q/K dead -> region becomes P

  u16* ldsP = ldsQK + wv * 32 * P_S;  // wave-private slice

#pragma unroll
  for (int ht = 0; ht < 2; ++ht)
#pragma unroll
    for (int r = 0; r < 4; ++r) {
      float m = -1e30f;
#pragma unroll
      for (int gt = 0; gt < 8; ++gt) m = fmaxf(m, e[ht][gt][r]);
#pragma unroll
      for (int off = 1; off < 16; off <<= 1) m = fmaxf(m, __shfl_xor(m, off));
      float s = 0.f;
#pragma unroll
      for (int gt = 0; gt < 8; ++gt) {
        float p = __expf(e[ht][gt][r] - m);
        e[ht][gt][r] = p;
        s += p;
      }
#pragma unroll
      for (int off = 1; off < 16; off <<= 1) s += __shfl_xor(s, off);
      const float inv = 1.f / s;
      const int hh = ht * 16 + lg * 4 + r;
#pragma unroll
      for (int gt = 0; gt < 8; ++gt)
        ldsP[hh * P_S + gt * 16 + col] = f16_rn(e[ht][gt][r] * inv);
    }

  f32x4 o[2][16];
#pragma unroll
  for (int ht = 0; ht < 2; ++ht)
#pragma unroll
    for (int ct = 0; ct < 16; ++ct) o[ht][ct] = zero;

#pragma unroll
  for (int ks = 0; ks < 4; ++ks) {
    half8 ap[2];
#pragma unroll
    for (int ht = 0; ht < 2; ++ht)
      ap[ht] = *reinterpret_cast<const half8*>(
          &ldsP[(ht * 16 + col) * P_S + ks * 32 + lg * 8]);
#pragma unroll
    for (int ct = 0; ct < 16; ++ct) {
      const half8 bv_ = *reinterpret_cast<const half8*>(
          vbase + ((ks * 4 + lg) * COUT_ + ct * 16 + col) * 8);
#pragma unroll
      for (int ht = 0; ht < 2; ++ht)
        o[ht][ct] = __builtin_amdgcn_mfma_f32_16x16x32_f16(ap[ht], bv_, o[ht][ct], 0, 0, 0);
    }
  }

  if (EPI == 1) {
    u16* ldsX = ldsQK;  // reuse
    u16* dst_col = out_tmp + ((size_t)(b * W_ + w) << 15);
#pragma unroll
    for (int ctg = 0; ctg < 4; ++ctg) {
      __syncthreads();
#pragma unroll
      for (int j = 0; j < 4; ++j) {
        const int ct    = ctg * 4 + j;
        const int c_loc = j * 16 + col;
#pragma unroll
        for (int ht = 0; ht < 2; ++ht) {
          const int hbase = wv * 32 + ht * 16 + lg * 4;
          half4 pk;
#pragma unroll
          for (int r = 0; r < 4; ++r) pk[r] = (_Float16)o[ht][ct][r];
          *reinterpret_cast<half4*>(&ldsX[c_loc * XP_S + hbase]) = pk;
        }
      }
      __syncthreads();
      const int c_loc = t >> 2;
      const int h0    = (t & 3) * 32;
      u16* dp = dst_col + (ctg * 64 + c_loc) * 128 + h0;
#pragma unroll
      for (int k = 0; k < 4; ++k)
        *reinterpret_cast<half8*>(dp + k * 8) =
            *reinterpret_cast<const half8*>(&ldsX[c_loc * XP_S + h0 + k * 8]);
    }
  } else {
    float* outp = out + (size_t)b * COUT_ * HW_ + w;
#pragma unroll
    for (int ht = 0; ht < 2; ++ht)
#pragma unroll
      for (int ct = 0; ct < 16; ++ct)
#pragma unroll
        for (int r = 0; r < 4; ++r) {
          int hrow = wv * 32 + ht * 16 + lg * 4 + r;
          int c = ct * 16 + col;
          outp[((size_t)c * H_ + hrow) * W_] = o[ht][ct][r];
        }
  }
}

// ---------------------------------------------------------------------------
// Kernel 3: out_tmp[b][w][f] fp16 -> out[b][f][w] fp32 (unchanged).
// ---------------------------------------------------------------------------
__global__ void __launch_bounds__(256) transpose_kernel(
    const u16* __restrict__ T, float* __restrict__ out) {
  __shared__ float lds[64 * 132];
  const int t   = threadIdx.x;
  const int bid = blockIdx.x;
  const int b   = bid >> 9;
  const int ft  = bid & 511;  // f-tile of 64

  {
    const int w  = t >> 1;
    const int fo = (t & 1) * 32;
    const u16* src = T + ((size_t)(b * W_ + w) << 15) + ft * 64 + fo;
#pragma unroll
    for (int k = 0; k < 4; ++k) {
      half8 v = *reinterpret_cast<const half8*>(src + k * 8);
#pragma unroll
      for (int e = 0; e < 8; ++e)
        lds[(fo + k * 8 + e) * 132 + w] = (float)v[e];
    }
  }
  __syncthreads();
  {
    const int f_loc = t >> 2;
    const int w0    = (t & 3) * 32;
    float* dst = out + (size_t)b * (COUT_ * HW_) + (size_t)(ft * 64 + f_loc) * 128 + w0;
#pragma unroll
    for (int k = 0; k < 8; ++k) {
      f4 v4;
#pragma unroll
      for (int e = 0; e < 4; ++e) v4[e] = lds[f_loc * 132 + w0 + k * 4 + e];
      *reinterpret_cast<f4*>(dst + k * 4) = v4;
    }
  }
}

extern "C" void kernel_launch(void* const* d_in, const int* in_sizes, int n_in,
                              void* d_out, int out_size, void* d_ws, size_t ws_size,
                              hipStream_t stream) {
  const float* flow   = (const float*)d_in[0];
  const float* de_out = (const float*)d_in[1];
  const float* Wq = (const float*)d_in[2];
  const float* bq = (const float*)d_in[3];
  const float* Wk = (const float*)d_in[4];
  const float* bk = (const float*)d_in[5];
  const float* Wv = (const float*)d_in[6];
  const float* bv = (const float*)d_in[7];
  float* out = (float*)d_out;

  u16* Qws = (u16*)d_ws;                 // [b][w][h][d]            fp16
  u16* Kws = Qws + Q_ELEMS;              // [b][w][h][d]            fp16
  u16* Vws = Kws + Q_ELEMS;              // [b][w][g>>3][c][g&7]    fp16
  u16* W16 = Vws + V_ELEMS;              // [Wk16|Wq16|Wv16]        fp16
  u16* Tws = W16 + W16_ELEMS;            // [b][w][c][h]            fp16

  wconv_kernel<<<96, 256, 0, stream>>>(Wk, Wq, Wv, W16);
  qkv_kernel<<<2 * B_ * H_ * 2, 256, 0, stream>>>(flow, de_out, W16, bq, bk, bv,
                                                  Qws, Kws, Vws);
  if (ws_size >= (size_t)WS_NEED) {
    attn_kernel<1><<<B_ * W_, 256, 0, stream>>>(Qws, Kws, Vws, Tws, out);
    transpose_kernel<<<B_ * 512, 256, 0, stream>>>(Tws, out);
  } else {
    attn_kernel<0><<<B_ * W_, 256, 0, stream>>>(Qws, Kws, Vws, Tws, out);
  }
}